// Round 1
// baseline (1180.899 us; speedup 1.0000x reference)
//
#include <hip/hip_runtime.h>

typedef __bf16 bf16x8 __attribute__((ext_vector_type(8)));
typedef float f32x4 __attribute__((ext_vector_type(4)));

#define T_TOK 1024
#define DIN   2048
#define NH    32
#define NKV   8
#define HD    64

__device__ __forceinline__ unsigned short f2bf(float f) {
  unsigned int u = __float_as_uint(f);
  unsigned int r = (u + 0x7fffu + ((u >> 16) & 1u)) >> 16;
  return (unsigned short)r;
}

// ---------------- fp32 -> bf16 convert (vectorized, grid-stride) -------------
__global__ void k_cvt(const float* __restrict__ in, unsigned short* __restrict__ out, int n) {
  int idx = blockIdx.x * blockDim.x + threadIdx.x;
  int stride = gridDim.x * blockDim.x;
  for (int i = idx * 4; i < n; i += stride * 4) {
    float4 v = *reinterpret_cast<const float4*>(in + i);
    ushort4 o;
    o.x = f2bf(v.x); o.y = f2bf(v.y); o.z = f2bf(v.z); o.w = f2bf(v.w);
    *reinterpret_cast<ushort4*>(out + i) = o;
  }
}

// ---------------- bf16 MFMA GEMM: C[M][N] = A[M][K] * B[N][K]^T --------------
// 128x128 block tile, 4 waves (2x2), each wave 64x64 via 4x4 16x16x32 frags.
// Direct-global fragment loads (operands are L2/L3 resident).
__global__ __launch_bounds__(256) void k_gemm_bt(
    const unsigned short* __restrict__ A, const unsigned short* __restrict__ B,
    float* __restrict__ C, int M, int N, int K) {
  const int lane = threadIdx.x & 63;
  const int wave = threadIdx.x >> 6;
  const int wm = wave >> 1, wn = wave & 1;
  const int lr = lane & 15, lk = lane >> 4;
  const int brow = blockIdx.y * 128 + wm * 64;
  const int bcol = blockIdx.x * 128 + wn * 64;

  f32x4 acc[4][4];
#pragma unroll
  for (int i = 0; i < 4; i++)
#pragma unroll
    for (int j = 0; j < 4; j++) acc[i][j] = (f32x4){0.f, 0.f, 0.f, 0.f};

  const unsigned short* Ap = A + (long)(brow + lr) * K + lk * 8;
  const unsigned short* Bp = B + (long)(bcol + lr) * K + lk * 8;

  for (int kk = 0; kk < K; kk += 32) {
    bf16x8 a[4], b[4];
#pragma unroll
    for (int i = 0; i < 4; i++)
      a[i] = *reinterpret_cast<const bf16x8*>(Ap + (long)i * 16 * K + kk);
#pragma unroll
    for (int j = 0; j < 4; j++)
      b[j] = *reinterpret_cast<const bf16x8*>(Bp + (long)j * 16 * K + kk);
#pragma unroll
    for (int i = 0; i < 4; i++)
#pragma unroll
      for (int j = 0; j < 4; j++)
        acc[i][j] = __builtin_amdgcn_mfma_f32_16x16x32_bf16(a[i], b[j], acc[i][j], 0, 0, 0);
  }

#pragma unroll
  for (int i = 0; i < 4; i++)
#pragma unroll
    for (int j = 0; j < 4; j++)
#pragma unroll
      for (int p = 0; p < 4; p++)
        C[(long)(brow + i * 16 + lk * 4 + p) * N + (bcol + j * 16 + lr)] = acc[i][j][p];
}

// ---------------- fused RMSNorm + RoPE (in place), one wave per (t, head) ----
__global__ void k_norm_rope(float* __restrict__ q_lin, float* __restrict__ k_lin,
                            const float* __restrict__ cosT, const float* __restrict__ sinT,
                            const float* __restrict__ qw, const float* __restrict__ kw) {
  int gw = (blockIdx.x * blockDim.x + threadIdx.x) >> 6;
  int lane = threadIdx.x & 63;
  int t = gw / (NH + NKV);
  int hh = gw % (NH + NKV);
  if (t >= T_TOK) return;
  float* base;
  const float* w;
  if (hh < NH) { base = q_lin + (long)t * (NH * HD) + hh * HD; w = qw; }
  else         { base = k_lin + (long)t * (NKV * HD) + (hh - NH) * HD; w = kw; }
  float v = base[lane];
  float ss = v * v;
#pragma unroll
  for (int off = 1; off < 64; off <<= 1) ss += __shfl_xor(ss, off);
  float xn = v * rsqrtf(ss * (1.0f / HD) + 1e-6f) * w[lane];
  float other = __shfl_xor(xn, 32);
  float c = cosT[t * HD + lane], s = sinT[t * HD + lane];
  base[lane] = xn * c + (lane < 32 ? -other : other) * s;
}

// ---------------- causal GQA attention, one block per (head, q-row) ----------
__global__ __launch_bounds__(256) void k_attn(
    const float* __restrict__ qf, const float* __restrict__ kf,
    const float* __restrict__ vf, unsigned short* __restrict__ ao) {
  __shared__ float qs[HD];
  __shared__ float sc[T_TOK];
  __shared__ float red[4];
  __shared__ float part[4][HD];
  int bid = blockIdx.x;
  int h = bid >> 10;
  int t = bid & 1023;
  int kvh = h >> 2;  // GROUP = 4
  int tid = threadIdx.x;
  if (tid < HD) qs[tid] = qf[(long)t * (NH * HD) + h * HD + tid];
  __syncthreads();
  int n = t + 1;
  float lmax = -3.0e38f;
  for (int s = tid; s < n; s += 256) {
    const float* kr = kf + (long)s * (NKV * HD) + kvh * HD;
    float acc = 0.f;
#pragma unroll
    for (int d = 0; d < HD; d += 4) {
      float4 k4 = *reinterpret_cast<const float4*>(kr + d);
      acc += qs[d] * k4.x + qs[d + 1] * k4.y + qs[d + 2] * k4.z + qs[d + 3] * k4.w;
    }
    float sv = acc * 0.125f;  // 1/sqrt(64)
    sc[s] = sv;
    lmax = fmaxf(lmax, sv);
  }
#pragma unroll
  for (int off = 1; off < 64; off <<= 1) lmax = fmaxf(lmax, __shfl_xor(lmax, off));
  if ((tid & 63) == 0) red[tid >> 6] = lmax;
  __syncthreads();
  float m = fmaxf(fmaxf(red[0], red[1]), fmaxf(red[2], red[3]));
  __syncthreads();
  float lsum = 0.f;
  for (int s = tid; s < n; s += 256) {
    float p = __expf(sc[s] - m);
    sc[s] = p;
    lsum += p;
  }
#pragma unroll
  for (int off = 1; off < 64; off <<= 1) lsum += __shfl_xor(lsum, off);
  if ((tid & 63) == 0) red[tid >> 6] = lsum;
  __syncthreads();
  float S = red[0] + red[1] + red[2] + red[3];
  int d = tid & 63, sg = tid >> 6;
  float o = 0.f;
  for (int s = sg; s < n; s += 4)
    o += sc[s] * vf[(long)s * (NKV * HD) + kvh * HD + d];
  part[sg][d] = o;
  __syncthreads();
  if (tid < HD) {
    float tot = (part[0][tid] + part[1][tid]) + (part[2][tid] + part[3][tid]);
    ao[(long)t * (NH * HD) + h * HD + tid] = f2bf(tot / S);
  }
}

extern "C" void kernel_launch(void* const* d_in, const int* in_sizes, int n_in,
                              void* d_out, int out_size, void* d_ws, size_t ws_size,
                              hipStream_t stream) {
  const float* x    = (const float*)d_in[0];
  const float* cosT = (const float*)d_in[3];
  const float* sinT = (const float*)d_in[5];
  const float* Wq   = (const float*)d_in[7];
  const float* Wk   = (const float*)d_in[8];
  const float* Wv   = (const float*)d_in[9];
  const float* Wo   = (const float*)d_in[10];
  const float* qw   = (const float*)d_in[11];
  const float* kw   = (const float*)d_in[12];
  float* out = (float*)d_out;

  char* ws = (char*)d_ws;
  unsigned short* xb   = (unsigned short*)(ws);
  unsigned short* Wqb  = (unsigned short*)(ws + 4194304);
  unsigned short* Wkb  = (unsigned short*)(ws + 12582912);
  unsigned short* Wvb  = (unsigned short*)(ws + 14680064);
  unsigned short* Wob  = (unsigned short*)(ws + 16777216);
  float* q_lin = (float*)(ws + 25165824);
  float* k_lin = (float*)(ws + 33554432);
  float* v_lin = (float*)(ws + 35651584);
  unsigned short* ao = (unsigned short*)(ws + 37748736);

  // fp32 -> bf16 operand conversion
  k_cvt<<<1024, 256, 0, stream>>>(x,  xb,  T_TOK * DIN);
  k_cvt<<<2048, 256, 0, stream>>>(Wq, Wqb, 2048 * 2048);
  k_cvt<<<512,  256, 0, stream>>>(Wk, Wkb, 512 * 2048);
  k_cvt<<<512,  256, 0, stream>>>(Wv, Wvb, 512 * 2048);
  k_cvt<<<2048, 256, 0, stream>>>(Wo, Wob, 2048 * 2048);

  // QKV projections (C = A * B^T)
  k_gemm_bt<<<dim3(16, 8), 256, 0, stream>>>(xb, Wqb, q_lin, 1024, 2048, 2048);
  k_gemm_bt<<<dim3(4, 8),  256, 0, stream>>>(xb, Wkb, k_lin, 1024, 512, 2048);
  k_gemm_bt<<<dim3(4, 8),  256, 0, stream>>>(xb, Wvb, v_lin, 1024, 512, 2048);

  // RMSNorm + RoPE on q and k (in place, fp32)
  k_norm_rope<<<(T_TOK * (NH + NKV) * 64) / 256, 256, 0, stream>>>(
      q_lin, k_lin, cosT, sinT, qw, kw);

  // causal GQA attention -> bf16 [T][H*HD]
  k_attn<<<NH * T_TOK, 256, 0, stream>>>(q_lin, k_lin, v_lin, ao);

  // output projection -> fp32 d_out
  k_gemm_bt<<<dim3(16, 8), 256, 0, stream>>>(ao, Wob, out, 1024, 2048, 2048);
}

// Round 2
// 434.328 us; speedup vs baseline: 2.7189x; 2.7189x over previous
//
#include <hip/hip_runtime.h>

typedef __bf16 bf16x8 __attribute__((ext_vector_type(8)));
typedef float f32x4 __attribute__((ext_vector_type(4)));

#define T_TOK 1024
#define DIN   2048
#define NH    32
#define NKV   8
#define HD    64

__device__ __forceinline__ unsigned short f2bf(float f) {
  unsigned int u = __float_as_uint(f);
  unsigned int r = (u + 0x7fffu + ((u >> 16) & 1u)) >> 16;
  return (unsigned short)r;
}

// ---------------- fp32 -> bf16 convert (vectorized, grid-stride) -------------
__global__ void k_cvt(const float* __restrict__ in, unsigned short* __restrict__ out, int n) {
  int idx = blockIdx.x * blockDim.x + threadIdx.x;
  int stride = gridDim.x * blockDim.x;
  for (int i = idx * 4; i < n; i += stride * 4) {
    float4 v = *reinterpret_cast<const float4*>(in + i);
    ushort4 o;
    o.x = f2bf(v.x); o.y = f2bf(v.y); o.z = f2bf(v.z); o.w = f2bf(v.w);
    *reinterpret_cast<ushort4*>(out + i) = o;
  }
}

// ---------------- bf16 MFMA GEMM: C[M][N] = A[M][K] * B[N][K]^T --------------
__global__ __launch_bounds__(256) void k_gemm_bt(
    const unsigned short* __restrict__ A, const unsigned short* __restrict__ B,
    float* __restrict__ C, int M, int N, int K) {
  const int lane = threadIdx.x & 63;
  const int wave = threadIdx.x >> 6;
  const int wm = wave >> 1, wn = wave & 1;
  const int lr = lane & 15, lk = lane >> 4;
  const int brow = blockIdx.y * 128 + wm * 64;
  const int bcol = blockIdx.x * 128 + wn * 64;

  f32x4 acc[4][4];
#pragma unroll
  for (int i = 0; i < 4; i++)
#pragma unroll
    for (int j = 0; j < 4; j++) acc[i][j] = (f32x4){0.f, 0.f, 0.f, 0.f};

  const unsigned short* Ap = A + (long)(brow + lr) * K + lk * 8;
  const unsigned short* Bp = B + (long)(bcol + lr) * K + lk * 8;

  for (int kk = 0; kk < K; kk += 32) {
    bf16x8 a[4], b[4];
#pragma unroll
    for (int i = 0; i < 4; i++)
      a[i] = *reinterpret_cast<const bf16x8*>(Ap + (long)i * 16 * K + kk);
#pragma unroll
    for (int j = 0; j < 4; j++)
      b[j] = *reinterpret_cast<const bf16x8*>(Bp + (long)j * 16 * K + kk);
#pragma unroll
    for (int i = 0; i < 4; i++)
#pragma unroll
      for (int j = 0; j < 4; j++)
        acc[i][j] = __builtin_amdgcn_mfma_f32_16x16x32_bf16(a[i], b[j], acc[i][j], 0, 0, 0);
  }

#pragma unroll
  for (int i = 0; i < 4; i++)
#pragma unroll
    for (int j = 0; j < 4; j++)
#pragma unroll
      for (int p = 0; p < 4; p++)
        C[(long)(brow + i * 16 + lk * 4 + p) * N + (bcol + j * 16 + lr)] = acc[i][j][p];
}

// ---------------- fused RMSNorm + RoPE -> bf16, one wave per (t, head) -------
__global__ void k_norm_rope(const float* __restrict__ q_lin, const float* __restrict__ k_lin,
                            unsigned short* __restrict__ qb, unsigned short* __restrict__ kb,
                            const float* __restrict__ cosT, const float* __restrict__ sinT,
                            const float* __restrict__ qw, const float* __restrict__ kw) {
  int gw = (blockIdx.x * blockDim.x + threadIdx.x) >> 6;
  int lane = threadIdx.x & 63;
  int t = gw / (NH + NKV);
  int hh = gw % (NH + NKV);
  if (t >= T_TOK) return;
  const float* base;
  unsigned short* ob;
  const float* w;
  if (hh < NH) {
    base = q_lin + (long)t * (NH * HD) + hh * HD;
    ob   = qb    + (long)t * (NH * HD) + hh * HD;
    w = qw;
  } else {
    int kh = hh - NH;
    base = k_lin + (long)t * (NKV * HD) + kh * HD;
    ob   = kb    + (long)t * (NKV * HD) + kh * HD;
    w = kw;
  }
  float v = base[lane];
  float ss = v * v;
#pragma unroll
  for (int off = 1; off < 64; off <<= 1) ss += __shfl_xor(ss, off);
  float xn = v * rsqrtf(ss * (1.0f / HD) + 1e-6f) * w[lane];
  float other = __shfl_xor(xn, 32);
  float c = cosT[t * HD + lane], s = sinT[t * HD + lane];
  ob[lane] = f2bf(xn * c + (lane < 32 ? -other : other) * s);
}

// ---------------- V transpose: [1024][512] f32 -> [512][1024] bf16 -----------
__global__ __launch_bounds__(256) void k_vt(const float* __restrict__ in,
                                            unsigned short* __restrict__ out) {
  __shared__ float t[32][33];
  int tx = threadIdx.x & 31, ty = threadIdx.x >> 5;  // 32x8
  int r0 = blockIdx.y * 32;  // token dim
  int c0 = blockIdx.x * 32;  // feature dim
#pragma unroll
  for (int r = 0; r < 4; r++)
    t[ty + r * 8][tx] = in[(long)(r0 + ty + r * 8) * 512 + c0 + tx];
  __syncthreads();
#pragma unroll
  for (int r = 0; r < 4; r++)
    out[(long)(c0 + ty + r * 8) * 1024 + r0 + tx] = f2bf(t[tx][ty + r * 8]);
}

// ---------------- flash attention: one block per (head, 64-q-tile) -----------
// 4 waves, each owns 16 q rows. KV tiles of 64. S and PV via 16x16x32 MFMA.
__global__ __launch_bounds__(256) void k_flash(
    const unsigned short* __restrict__ qb, const unsigned short* __restrict__ kb,
    const unsigned short* __restrict__ vtb, unsigned short* __restrict__ ao) {
  __shared__ unsigned short plds[4 * 16 * 64];  // per-wave 16x64 bf16 strip, XOR-swizzled
  const int h = blockIdx.y;
  const int qt = blockIdx.x;
  const int kvh = h >> 2;  // GROUP = 4
  const int lane = threadIdx.x & 63;
  const int wave = threadIdx.x >> 6;
  const int lr = lane & 15, lk = lane >> 4;
  const int qrow = qt * 64 + wave * 16;  // wave's q rows: qrow..qrow+15
  char* pbase = (char*)plds + wave * 2048;

  // Q A-fragments, held across the whole KV loop (2 k-steps over d)
  const unsigned short* qp = qb + (long)(qrow + lr) * (NH * HD) + h * HD + lk * 8;
  bf16x8 qa0 = *reinterpret_cast<const bf16x8*>(qp);
  bf16x8 qa1 = *reinterpret_cast<const bf16x8*>(qp + 32);

  f32x4 o[4];
#pragma unroll
  for (int f = 0; f < 4; f++) o[f] = (f32x4){0.f, 0.f, 0.f, 0.f};
  float m[4] = {-3.0e38f, -3.0e38f, -3.0e38f, -3.0e38f};
  float l[4] = {0.f, 0.f, 0.f, 0.f};

  const int ntiles = qt + 1;
  for (int tile = 0; tile < ntiles; ++tile) {
    const int s0 = tile * 64;
    // ---- S = Q K^T (strip 16 q x 64 k) ----
    f32x4 sacc[4];
#pragma unroll
    for (int f = 0; f < 4; f++) sacc[f] = (f32x4){0.f, 0.f, 0.f, 0.f};
    const unsigned short* kp = kb + (long)(s0 + lr) * (NKV * HD) + kvh * HD + lk * 8;
#pragma unroll
    for (int f = 0; f < 4; f++) {
      bf16x8 kf0 = *reinterpret_cast<const bf16x8*>(kp + (long)f * 16 * (NKV * HD));
      bf16x8 kf1 = *reinterpret_cast<const bf16x8*>(kp + (long)f * 16 * (NKV * HD) + 32);
      sacc[f] = __builtin_amdgcn_mfma_f32_16x16x32_bf16(qa0, kf0, sacc[f], 0, 0, 0);
      sacc[f] = __builtin_amdgcn_mfma_f32_16x16x32_bf16(qa1, kf1, sacc[f], 0, 0, 0);
    }
    const bool diag = (tile == qt);
    // ---- online softmax (per reg p = q-row lk*4+p) ----
    float rscale[4];
#pragma unroll
    for (int p = 0; p < 4; p++) {
      const int qrel = wave * 16 + lk * 4 + p;  // q row within 64-block
      float sv[4];
#pragma unroll
      for (int f = 0; f < 4; f++) {
        sv[f] = sacc[f][p] * 0.125f;
        if (diag && (f * 16 + lr) > qrel) sv[f] = -3.0e38f;
      }
      float tm = fmaxf(fmaxf(sv[0], sv[1]), fmaxf(sv[2], sv[3]));
      tm = fmaxf(tm, __shfl_xor(tm, 1));
      tm = fmaxf(tm, __shfl_xor(tm, 2));
      tm = fmaxf(tm, __shfl_xor(tm, 4));
      tm = fmaxf(tm, __shfl_xor(tm, 8));
      float mn = fmaxf(m[p], tm);
      float r = __expf(m[p] - mn);
      m[p] = mn;
      rscale[p] = r;
      float ps = 0.f;
      const int row = lk * 4 + p;
      const int swz = (row & 7) << 4;
#pragma unroll
      for (int f = 0; f < 4; f++) {
        float pv = __expf(sv[f] - mn);
        ps += pv;
        int cb = (f * 16 + lr) * 2;
        *reinterpret_cast<unsigned short*>(pbase + row * 128 + (cb ^ swz)) = f2bf(pv);
      }
      l[p] = l[p] * r + ps;
    }
    // ---- rescale O ----
#pragma unroll
    for (int fd = 0; fd < 4; fd++)
#pragma unroll
      for (int p = 0; p < 4; p++) o[fd][p] *= rscale[p];
    // ---- PV: O += P * V ----
    const unsigned short* vp = vtb + (long)(kvh * HD + lr) * T_TOK + s0 + lk * 8;
#pragma unroll
    for (int ks = 0; ks < 2; ks++) {
      const int rowr = lr;
      bf16x8 pa = *reinterpret_cast<const bf16x8*>(
          pbase + rowr * 128 + ((ks * 64 + lk * 16) ^ ((rowr & 7) << 4)));
#pragma unroll
      for (int fd = 0; fd < 4; fd++) {
        bf16x8 vb = *reinterpret_cast<const bf16x8*>(vp + (long)fd * 16 * T_TOK + ks * 32);
        o[fd] = __builtin_amdgcn_mfma_f32_16x16x32_bf16(pa, vb, o[fd], 0, 0, 0);
      }
    }
  }
  // ---- finalize: row-sum l across the 16-lane group, normalize, store ----
#pragma unroll
  for (int p = 0; p < 4; p++) {
    float lv = l[p];
    lv += __shfl_xor(lv, 1);
    lv += __shfl_xor(lv, 2);
    lv += __shfl_xor(lv, 4);
    lv += __shfl_xor(lv, 8);
    l[p] = lv;
  }
#pragma unroll
  for (int fd = 0; fd < 4; fd++)
#pragma unroll
    for (int p = 0; p < 4; p++) {
      int qg = qrow + lk * 4 + p;
      int d = fd * 16 + lr;
      ao[(long)qg * (NH * HD) + h * HD + d] = f2bf(o[fd][p] / l[p]);
    }
}

extern "C" void kernel_launch(void* const* d_in, const int* in_sizes, int n_in,
                              void* d_out, int out_size, void* d_ws, size_t ws_size,
                              hipStream_t stream) {
  const float* x    = (const float*)d_in[0];
  const float* cosT = (const float*)d_in[3];
  const float* sinT = (const float*)d_in[5];
  const float* Wq   = (const float*)d_in[7];
  const float* Wk   = (const float*)d_in[8];
  const float* Wv   = (const float*)d_in[9];
  const float* Wo   = (const float*)d_in[10];
  const float* qw   = (const float*)d_in[11];
  const float* kw   = (const float*)d_in[12];
  float* out = (float*)d_out;

  char* ws = (char*)d_ws;
  unsigned short* xb   = (unsigned short*)(ws);              // 4 MB
  unsigned short* Wqb  = (unsigned short*)(ws + (4u << 20)); // 8 MB
  unsigned short* Wkb  = (unsigned short*)(ws + (12u << 20)); // 2 MB
  unsigned short* Wvb  = (unsigned short*)(ws + (14u << 20)); // 2 MB
  unsigned short* Wob  = (unsigned short*)(ws + (16u << 20)); // 8 MB
  float* q_lin = (float*)(ws + (24u << 20));                 // 8 MB
  float* k_lin = (float*)(ws + (32u << 20));                 // 2 MB
  float* v_lin = (float*)(ws + (34u << 20));                 // 2 MB
  unsigned short* ao  = (unsigned short*)(ws + (36u << 20)); // 4 MB
  unsigned short* qbb = (unsigned short*)(ws + (40u << 20)); // 4 MB
  unsigned short* kbb = (unsigned short*)(ws + (44u << 20)); // 1 MB
  unsigned short* vtb = (unsigned short*)(ws + (45u << 20)); // 1 MB

  // fp32 -> bf16 operand conversion
  k_cvt<<<1024, 256, 0, stream>>>(x,  xb,  T_TOK * DIN);
  k_cvt<<<2048, 256, 0, stream>>>(Wq, Wqb, 2048 * 2048);
  k_cvt<<<512,  256, 0, stream>>>(Wk, Wkb, 512 * 2048);
  k_cvt<<<512,  256, 0, stream>>>(Wv, Wvb, 512 * 2048);
  k_cvt<<<2048, 256, 0, stream>>>(Wo, Wob, 2048 * 2048);

  // QKV projections (C = A * B^T), fp32 out
  k_gemm_bt<<<dim3(16, 8), 256, 0, stream>>>(xb, Wqb, q_lin, 1024, 2048, 2048);
  k_gemm_bt<<<dim3(4, 8),  256, 0, stream>>>(xb, Wkb, k_lin, 1024, 512, 2048);
  k_gemm_bt<<<dim3(4, 8),  256, 0, stream>>>(xb, Wvb, v_lin, 1024, 512, 2048);

  // RMSNorm + RoPE -> bf16 q/k
  k_norm_rope<<<(T_TOK * (NH + NKV) * 64) / 256, 256, 0, stream>>>(
      q_lin, k_lin, qbb, kbb, cosT, sinT, qw, kw);

  // V^T bf16 for PV B-operand
  k_vt<<<dim3(16, 32), 256, 0, stream>>>(v_lin, vtb);

  // flash attention -> bf16 [T][H*HD]
  k_flash<<<dim3(16, 32), 256, 0, stream>>>(qbb, kbb, vtb, ao);

  // output projection -> fp32 d_out
  k_gemm_bt<<<dim3(16, 8), 256, 0, stream>>>(ao, Wob, out, 1024, 2048, 2048);
}

// Round 3
// 258.492 us; speedup vs baseline: 4.5684x; 1.6802x over previous
//
#include <hip/hip_runtime.h>

typedef __bf16 bf16x8 __attribute__((ext_vector_type(8)));
typedef float f32x4 __attribute__((ext_vector_type(4)));

#define T_TOK 1024
#define DIN   2048
#define NH    32
#define NKV   8
#define HD    64

__device__ __forceinline__ unsigned short f2bf(float f) {
  unsigned int u = __float_as_uint(f);
  unsigned int r = (u + 0x7fffu + ((u >> 16) & 1u)) >> 16;
  return (unsigned short)r;
}

__device__ __forceinline__ void glds16(const void* g, void* lds) {
  __builtin_amdgcn_global_load_lds(
      (const __attribute__((address_space(1))) void*)g,
      (__attribute__((address_space(3))) void*)lds, 16, 0, 0);
}

// ---------------- fp32 -> bf16 convert (vectorized, grid-stride) -------------
__global__ void k_cvt(const float* __restrict__ in, unsigned short* __restrict__ out, int n) {
  int idx = blockIdx.x * blockDim.x + threadIdx.x;
  int stride = gridDim.x * blockDim.x;
  for (int i = idx * 4; i < n; i += stride * 4) {
    float4 v = *reinterpret_cast<const float4*>(in + i);
    ushort4 o;
    o.x = f2bf(v.x); o.y = f2bf(v.y); o.z = f2bf(v.z); o.w = f2bf(v.w);
    *reinterpret_cast<ushort4*>(out + i) = o;
  }
}

// ------- bf16 MFMA GEMM, LDS-staged 2-phase: C[M][N] = A[M][K] * B[N][K]^T ---
// BM=64 BN=128 BK=64, 4 waves (2x2), each wave 32x64 (2x4 frags).
// global_load_lds(16B) staging: linear LDS dest, inverse-swizzled global src,
// XOR-swizzled ds_read (T2: colbyte ^= (row&7)<<4).
__global__ __launch_bounds__(256) void k_gemm2(
    const unsigned short* __restrict__ A, const unsigned short* __restrict__ B,
    float* __restrict__ C, int N, int K) {
  __shared__ unsigned short As[2][64 * 64];
  __shared__ unsigned short Bs[2][128 * 64];
  const int lane = threadIdx.x & 63;
  const int wave = threadIdx.x >> 6;
  const int wm = wave >> 1, wn = wave & 1;
  const int lr = lane & 15, lk = lane >> 4;
  const int brow = blockIdx.y * 64;
  const int bcol = blockIdx.x * 128;

  // per-lane staging source base (inverse-swizzled column)
  const int srow = lane >> 3;                     // row within 8-row strip
  const int scol = ((lane & 7) ^ srow) * 8;       // element col (inverse swz)
  const unsigned short* Ag = A + (long)(brow + srow) * K + scol;
  const unsigned short* Bg = B + (long)(bcol + srow) * K + scol;

  f32x4 acc[2][4];
#pragma unroll
  for (int i = 0; i < 2; i++)
#pragma unroll
    for (int j = 0; j < 4; j++) acc[i][j] = (f32x4){0.f, 0.f, 0.f, 0.f};

  const int swz = (lr & 7) << 4;
  const int nt = K / 64;
  int cur = 0;

  // prologue: stage tile 0
#pragma unroll
  for (int i = 0; i < 2; i++) {
    int strip = i * 4 + wave;
    glds16(Ag + (long)strip * 8 * K, (char*)As[0] + strip * 1024);
  }
#pragma unroll
  for (int i = 0; i < 4; i++) {
    int strip = i * 4 + wave;
    glds16(Bg + (long)strip * 8 * K, (char*)Bs[0] + strip * 1024);
  }
  __syncthreads();

  for (int t = 0; t < nt; t++) {
    if (t + 1 < nt) {
      const int kk = (t + 1) * 64;
#pragma unroll
      for (int i = 0; i < 2; i++) {
        int strip = i * 4 + wave;
        glds16(Ag + (long)strip * 8 * K + kk, (char*)As[cur ^ 1] + strip * 1024);
      }
#pragma unroll
      for (int i = 0; i < 4; i++) {
        int strip = i * 4 + wave;
        glds16(Bg + (long)strip * 8 * K + kk, (char*)Bs[cur ^ 1] + strip * 1024);
      }
    }
    // compute current tile
#pragma unroll
    for (int s = 0; s < 2; s++) {
      bf16x8 a[2], b[4];
#pragma unroll
      for (int i = 0; i < 2; i++) {
        int row = wm * 32 + i * 16 + lr;
        a[i] = *reinterpret_cast<const bf16x8*>(
            (const char*)As[cur] + row * 128 + ((s * 64 + lk * 16) ^ swz));
      }
#pragma unroll
      for (int j = 0; j < 4; j++) {
        int row = wn * 64 + j * 16 + lr;
        b[j] = *reinterpret_cast<const bf16x8*>(
            (const char*)Bs[cur] + row * 128 + ((s * 64 + lk * 16) ^ swz));
      }
#pragma unroll
      for (int i = 0; i < 2; i++)
#pragma unroll
        for (int j = 0; j < 4; j++)
          acc[i][j] = __builtin_amdgcn_mfma_f32_16x16x32_bf16(a[i], b[j], acc[i][j], 0, 0, 0);
    }
    __syncthreads();
    cur ^= 1;
  }

#pragma unroll
  for (int i = 0; i < 2; i++)
#pragma unroll
    for (int j = 0; j < 4; j++)
#pragma unroll
      for (int p = 0; p < 4; p++)
        C[(long)(brow + wm * 32 + i * 16 + lk * 4 + p) * N + (bcol + wn * 64 + j * 16 + lr)] =
            acc[i][j][p];
}

// ---------------- fused RMSNorm + RoPE -> bf16, one wave per (t, head) -------
// reads fused qkv_lin [T][3072] (q cols 0..2047, k cols 2048..2559)
__global__ void k_norm_rope(const float* __restrict__ qkv_lin,
                            unsigned short* __restrict__ qb, unsigned short* __restrict__ kb,
                            const float* __restrict__ cosT, const float* __restrict__ sinT,
                            const float* __restrict__ qw, const float* __restrict__ kw) {
  int gw = (blockIdx.x * blockDim.x + threadIdx.x) >> 6;
  int lane = threadIdx.x & 63;
  int t = gw / (NH + NKV);
  int hh = gw % (NH + NKV);
  if (t >= T_TOK) return;
  const float* base;
  unsigned short* ob;
  const float* w;
  if (hh < NH) {
    base = qkv_lin + (long)t * 3072 + hh * HD;
    ob   = qb + (long)t * (NH * HD) + hh * HD;
    w = qw;
  } else {
    int kh = hh - NH;
    base = qkv_lin + (long)t * 3072 + 2048 + kh * HD;
    ob   = kb + (long)t * (NKV * HD) + kh * HD;
    w = kw;
  }
  float v = base[lane];
  float ss = v * v;
#pragma unroll
  for (int off = 1; off < 64; off <<= 1) ss += __shfl_xor(ss, off);
  float xn = v * rsqrtf(ss * (1.0f / HD) + 1e-6f) * w[lane];
  float other = __shfl_xor(xn, 32);
  float c = cosT[t * HD + lane], s = sinT[t * HD + lane];
  ob[lane] = f2bf(xn * c + (lane < 32 ? -other : other) * s);
}

// -------- V transpose: qkv_lin cols 2560.. (f32) -> [512][1024] bf16 ---------
__global__ __launch_bounds__(256) void k_vt(const float* __restrict__ qkv_lin,
                                            unsigned short* __restrict__ out) {
  __shared__ float t[32][33];
  int tx = threadIdx.x & 31, ty = threadIdx.x >> 5;  // 32x8
  int r0 = blockIdx.y * 32;  // token dim
  int c0 = blockIdx.x * 32;  // feature dim
#pragma unroll
  for (int r = 0; r < 4; r++)
    t[ty + r * 8][tx] = qkv_lin[(long)(r0 + ty + r * 8) * 3072 + 2560 + c0 + tx];
  __syncthreads();
#pragma unroll
  for (int r = 0; r < 4; r++)
    out[(long)(c0 + ty + r * 8) * 1024 + r0 + tx] = f2bf(t[tx][ty + r * 8]);
}

// ---------------- flash attention: one block per (head, 64-q-tile) -----------
__global__ __launch_bounds__(256) void k_flash(
    const unsigned short* __restrict__ qb, const unsigned short* __restrict__ kb,
    const unsigned short* __restrict__ vtb, unsigned short* __restrict__ ao) {
  __shared__ unsigned short plds[4 * 16 * 64];  // per-wave 16x64 bf16 strip, XOR-swizzled
  const int h = blockIdx.y;
  const int qt = gridDim.x - 1 - blockIdx.x;  // longest-first
  const int kvh = h >> 2;  // GROUP = 4
  const int lane = threadIdx.x & 63;
  const int wave = threadIdx.x >> 6;
  const int lr = lane & 15, lk = lane >> 4;
  const int qrow = qt * 64 + wave * 16;
  char* pbase = (char*)plds + wave * 2048;

  const unsigned short* qp = qb + (long)(qrow + lr) * (NH * HD) + h * HD + lk * 8;
  bf16x8 qa0 = *reinterpret_cast<const bf16x8*>(qp);
  bf16x8 qa1 = *reinterpret_cast<const bf16x8*>(qp + 32);

  f32x4 o[4];
#pragma unroll
  for (int f = 0; f < 4; f++) o[f] = (f32x4){0.f, 0.f, 0.f, 0.f};
  float m[4] = {-3.0e38f, -3.0e38f, -3.0e38f, -3.0e38f};
  float l[4] = {0.f, 0.f, 0.f, 0.f};

  const int ntiles = qt + 1;
  for (int tile = 0; tile < ntiles; ++tile) {
    const int s0 = tile * 64;
    f32x4 sacc[4];
#pragma unroll
    for (int f = 0; f < 4; f++) sacc[f] = (f32x4){0.f, 0.f, 0.f, 0.f};
    const unsigned short* kp = kb + (long)(s0 + lr) * (NKV * HD) + kvh * HD + lk * 8;
#pragma unroll
    for (int f = 0; f < 4; f++) {
      bf16x8 kf0 = *reinterpret_cast<const bf16x8*>(kp + (long)f * 16 * (NKV * HD));
      bf16x8 kf1 = *reinterpret_cast<const bf16x8*>(kp + (long)f * 16 * (NKV * HD) + 32);
      sacc[f] = __builtin_amdgcn_mfma_f32_16x16x32_bf16(qa0, kf0, sacc[f], 0, 0, 0);
      sacc[f] = __builtin_amdgcn_mfma_f32_16x16x32_bf16(qa1, kf1, sacc[f], 0, 0, 0);
    }
    const bool diag = (tile == qt);
    float rscale[4];
#pragma unroll
    for (int p = 0; p < 4; p++) {
      const int qrel = wave * 16 + lk * 4 + p;
      float sv[4];
#pragma unroll
      for (int f = 0; f < 4; f++) {
        sv[f] = sacc[f][p] * 0.125f;
        if (diag && (f * 16 + lr) > qrel) sv[f] = -3.0e38f;
      }
      float tm = fmaxf(fmaxf(sv[0], sv[1]), fmaxf(sv[2], sv[3]));
      tm = fmaxf(tm, __shfl_xor(tm, 1));
      tm = fmaxf(tm, __shfl_xor(tm, 2));
      tm = fmaxf(tm, __shfl_xor(tm, 4));
      tm = fmaxf(tm, __shfl_xor(tm, 8));
      float mn = fmaxf(m[p], tm);
      float r = __expf(m[p] - mn);
      m[p] = mn;
      rscale[p] = r;
      float ps = 0.f;
      const int row = lk * 4 + p;
      const int swzp = (row & 7) << 4;
#pragma unroll
      for (int f = 0; f < 4; f++) {
        float pv = __expf(sv[f] - mn);
        ps += pv;
        int cb = (f * 16 + lr) * 2;
        *reinterpret_cast<unsigned short*>(pbase + row * 128 + (cb ^ swzp)) = f2bf(pv);
      }
      l[p] = l[p] * r + ps;
    }
#pragma unroll
    for (int fd = 0; fd < 4; fd++)
#pragma unroll
      for (int p = 0; p < 4; p++) o[fd][p] *= rscale[p];
    const unsigned short* vp = vtb + (long)(kvh * HD + lr) * T_TOK + s0 + lk * 8;
#pragma unroll
    for (int ks = 0; ks < 2; ks++) {
      bf16x8 pa = *reinterpret_cast<const bf16x8*>(
          pbase + lr * 128 + ((ks * 64 + lk * 16) ^ ((lr & 7) << 4)));
#pragma unroll
      for (int fd = 0; fd < 4; fd++) {
        bf16x8 vb = *reinterpret_cast<const bf16x8*>(vp + (long)fd * 16 * T_TOK + ks * 32);
        o[fd] = __builtin_amdgcn_mfma_f32_16x16x32_bf16(pa, vb, o[fd], 0, 0, 0);
      }
    }
  }
#pragma unroll
  for (int p = 0; p < 4; p++) {
    float lv = l[p];
    lv += __shfl_xor(lv, 1);
    lv += __shfl_xor(lv, 2);
    lv += __shfl_xor(lv, 4);
    lv += __shfl_xor(lv, 8);
    l[p] = lv;
  }
#pragma unroll
  for (int fd = 0; fd < 4; fd++)
#pragma unroll
    for (int p = 0; p < 4; p++) {
      int qg = qrow + lk * 4 + p;
      int d = fd * 16 + lr;
      ao[(long)qg * (NH * HD) + d + h * HD] = f2bf(o[fd][p] / l[p]);
    }
}

extern "C" void kernel_launch(void* const* d_in, const int* in_sizes, int n_in,
                              void* d_out, int out_size, void* d_ws, size_t ws_size,
                              hipStream_t stream) {
  const float* x    = (const float*)d_in[0];
  const float* cosT = (const float*)d_in[3];
  const float* sinT = (const float*)d_in[5];
  const float* Wq   = (const float*)d_in[7];
  const float* Wk   = (const float*)d_in[8];
  const float* Wv   = (const float*)d_in[9];
  const float* Wo   = (const float*)d_in[10];
  const float* qw   = (const float*)d_in[11];
  const float* kw   = (const float*)d_in[12];
  float* out = (float*)d_out;

  char* ws = (char*)d_ws;
  unsigned short* xb    = (unsigned short*)(ws);               // 4 MB
  unsigned short* Wqkv  = (unsigned short*)(ws + (4u << 20));  // 12 MB [3072][2048]
  unsigned short* Wob   = (unsigned short*)(ws + (16u << 20)); // 8 MB
  float* qkv_lin = (float*)(ws + (24u << 20));                 // 12 MB [1024][3072]
  unsigned short* qbb = (unsigned short*)(ws + (36u << 20));   // 4 MB
  unsigned short* kbb = (unsigned short*)(ws + (40u << 20));   // 1 MB
  unsigned short* vtb = (unsigned short*)(ws + (41u << 20));   // 1 MB
  unsigned short* ao  = (unsigned short*)(ws + (42u << 20));   // 4 MB

  // fp32 -> bf16 operand conversion (Wq/Wk/Wv fused into one [3072][2048])
  k_cvt<<<512,  256, 0, stream>>>(x,  xb, T_TOK * DIN);
  k_cvt<<<1024, 256, 0, stream>>>(Wq, Wqkv,                2048 * 2048);
  k_cvt<<<256,  256, 0, stream>>>(Wk, Wqkv + 4u * 1048576, 512 * 2048);
  k_cvt<<<256,  256, 0, stream>>>(Wv, Wqkv + 5u * 1048576, 512 * 2048);
  k_cvt<<<1024, 256, 0, stream>>>(Wo, Wob,                 2048 * 2048);

  // fused QKV projection: [1024][3072] = x * Wqkv^T
  k_gemm2<<<dim3(24, 16), 256, 0, stream>>>(xb, Wqkv, qkv_lin, 3072, 2048);

  // RMSNorm + RoPE -> bf16 q/k
  k_norm_rope<<<(T_TOK * (NH + NKV) * 64) / 256, 256, 0, stream>>>(
      qkv_lin, qbb, kbb, cosT, sinT, qw, kw);

  // V^T bf16 for PV B-operand
  k_vt<<<dim3(16, 32), 256, 0, stream>>>(qkv_lin, vtb);

  // flash attention -> bf16 [T][H*HD]
  k_flash<<<dim3(16, 32), 256, 0, stream>>>(qbb, kbb, vtb, ao);

  // output projection -> fp32 d_out
  k_gemm2<<<dim3(16, 16), 256, 0, stream>>>(ao, Wob, out, 2048, 2048);
}

// Round 4
// 237.830 us; speedup vs baseline: 4.9653x; 1.0869x over previous
//
#include <hip/hip_runtime.h>

typedef __bf16 bf16x8 __attribute__((ext_vector_type(8)));
typedef float f32x4 __attribute__((ext_vector_type(4)));

#define T_TOK 1024
#define DIN   2048
#define NH    32
#define NKV   8
#define HD    64

__device__ __forceinline__ unsigned short f2bf(float f) {
  unsigned int u = __float_as_uint(f);
  unsigned int r = (u + 0x7fffu + ((u >> 16) & 1u)) >> 16;
  return (unsigned short)r;
}

__device__ __forceinline__ void glds16(const void* g, void* lds) {
  __builtin_amdgcn_global_load_lds(
      (const __attribute__((address_space(1))) void*)g,
      (__attribute__((address_space(3))) void*)lds, 16, 0, 0);
}

// ------------- fused fp32 -> bf16 convert for all 5 operands, 1 launch -------
__global__ __launch_bounds__(256) void k_cvt_all(
    const float* __restrict__ x,  const float* __restrict__ wq,
    const float* __restrict__ wk, const float* __restrict__ wv,
    const float* __restrict__ wo, unsigned short* __restrict__ xb,
    unsigned short* __restrict__ wqkv, unsigned short* __restrict__ wob) {
  const long NX = 1l << 21, NWQ = 1l << 22, NWK = 1l << 20, NWV = 1l << 20;
  long i4 = ((long)blockIdx.x * blockDim.x + threadIdx.x) * 4;
  const float* src;
  unsigned short* dst;
  long off;
  if (i4 < NX)                       { src = x;  dst = xb;   off = i4; }
  else if (i4 < NX + NWQ)            { src = wq; dst = wqkv; off = i4 - NX; }
  else if (i4 < NX + NWQ + NWK)      { src = wk; dst = wqkv + NWQ; off = i4 - NX - NWQ; }
  else if (i4 < NX + NWQ + NWK + NWV){ src = wv; dst = wqkv + NWQ + NWK; off = i4 - NX - NWQ - NWK; }
  else                               { src = wo; dst = wob;  off = i4 - NX - NWQ - NWK - NWV; }
  float4 v = *reinterpret_cast<const float4*>(src + off);
  ushort4 o;
  o.x = f2bf(v.x); o.y = f2bf(v.y); o.z = f2bf(v.z); o.w = f2bf(v.w);
  *reinterpret_cast<ushort4*>(dst + off) = o;
}

// ------- bf16 MFMA GEMM, LDS-staged 2-phase: C[M][N] = A[M][K] * B[N][K]^T ---
__global__ __launch_bounds__(256) void k_gemm2(
    const unsigned short* __restrict__ A, const unsigned short* __restrict__ B,
    float* __restrict__ C, int N, int K) {
  __shared__ unsigned short As[2][64 * 64];
  __shared__ unsigned short Bs[2][128 * 64];
  const int lane = threadIdx.x & 63;
  const int wave = threadIdx.x >> 6;
  const int wm = wave >> 1, wn = wave & 1;
  const int lr = lane & 15, lk = lane >> 4;
  const int brow = blockIdx.y * 64;
  const int bcol = blockIdx.x * 128;

  const int srow = lane >> 3;
  const int scol = ((lane & 7) ^ srow) * 8;
  const unsigned short* Ag = A + (long)(brow + srow) * K + scol;
  const unsigned short* Bg = B + (long)(bcol + srow) * K + scol;

  f32x4 acc[2][4];
#pragma unroll
  for (int i = 0; i < 2; i++)
#pragma unroll
    for (int j = 0; j < 4; j++) acc[i][j] = (f32x4){0.f, 0.f, 0.f, 0.f};

  const int swz = (lr & 7) << 4;
  const int nt = K / 64;
  int cur = 0;

#pragma unroll
  for (int i = 0; i < 2; i++) {
    int strip = i * 4 + wave;
    glds16(Ag + (long)strip * 8 * K, (char*)As[0] + strip * 1024);
  }
#pragma unroll
  for (int i = 0; i < 4; i++) {
    int strip = i * 4 + wave;
    glds16(Bg + (long)strip * 8 * K, (char*)Bs[0] + strip * 1024);
  }
  __syncthreads();

  for (int t = 0; t < nt; t++) {
    if (t + 1 < nt) {
      const int kk = (t + 1) * 64;
#pragma unroll
      for (int i = 0; i < 2; i++) {
        int strip = i * 4 + wave;
        glds16(Ag + (long)strip * 8 * K + kk, (char*)As[cur ^ 1] + strip * 1024);
      }
#pragma unroll
      for (int i = 0; i < 4; i++) {
        int strip = i * 4 + wave;
        glds16(Bg + (long)strip * 8 * K + kk, (char*)Bs[cur ^ 1] + strip * 1024);
      }
    }
#pragma unroll
    for (int s = 0; s < 2; s++) {
      bf16x8 a[2], b[4];
#pragma unroll
      for (int i = 0; i < 2; i++) {
        int row = wm * 32 + i * 16 + lr;
        a[i] = *reinterpret_cast<const bf16x8*>(
            (const char*)As[cur] + row * 128 + ((s * 64 + lk * 16) ^ swz));
      }
#pragma unroll
      for (int j = 0; j < 4; j++) {
        int row = wn * 64 + j * 16 + lr;
        b[j] = *reinterpret_cast<const bf16x8*>(
            (const char*)Bs[cur] + row * 128 + ((s * 64 + lk * 16) ^ swz));
      }
#pragma unroll
      for (int i = 0; i < 2; i++)
#pragma unroll
        for (int j = 0; j < 4; j++)
          acc[i][j] = __builtin_amdgcn_mfma_f32_16x16x32_bf16(a[i], b[j], acc[i][j], 0, 0, 0);
    }
    __syncthreads();
    cur ^= 1;
  }

#pragma unroll
  for (int i = 0; i < 2; i++)
#pragma unroll
    for (int j = 0; j < 4; j++)
#pragma unroll
      for (int p = 0; p < 4; p++)
        C[(long)(brow + wm * 32 + i * 16 + lk * 4 + p) * N + (bcol + wn * 64 + j * 16 + lr)] =
            acc[i][j][p];
}

// ---------------- fused RMSNorm + RoPE -> bf16, one wave per (t, head) -------
__global__ void k_norm_rope(const float* __restrict__ qkv_lin,
                            unsigned short* __restrict__ qb, unsigned short* __restrict__ kb,
                            const float* __restrict__ cosT, const float* __restrict__ sinT,
                            const float* __restrict__ qw, const float* __restrict__ kw) {
  int gw = (blockIdx.x * blockDim.x + threadIdx.x) >> 6;
  int lane = threadIdx.x & 63;
  int t = gw / (NH + NKV);
  int hh = gw % (NH + NKV);
  if (t >= T_TOK) return;
  const float* base;
  unsigned short* ob;
  const float* w;
  if (hh < NH) {
    base = qkv_lin + (long)t * 3072 + hh * HD;
    ob   = qb + (long)t * (NH * HD) + hh * HD;
    w = qw;
  } else {
    int kh = hh - NH;
    base = qkv_lin + (long)t * 3072 + 2048 + kh * HD;
    ob   = kb + (long)t * (NKV * HD) + kh * HD;
    w = kw;
  }
  float v = base[lane];
  float ss = v * v;
#pragma unroll
  for (int off = 1; off < 64; off <<= 1) ss += __shfl_xor(ss, off);
  float xn = v * rsqrtf(ss * (1.0f / HD) + 1e-6f) * w[lane];
  float other = __shfl_xor(xn, 32);
  float c = cosT[t * HD + lane], s = sinT[t * HD + lane];
  ob[lane] = f2bf(xn * c + (lane < 32 ? -other : other) * s);
}

// -------- V transpose: qkv_lin cols 2560.. (f32) -> [512][1024] bf16 ---------
__global__ __launch_bounds__(256) void k_vt(const float* __restrict__ qkv_lin,
                                            unsigned short* __restrict__ out) {
  __shared__ float t[32][33];
  int tx = threadIdx.x & 31, ty = threadIdx.x >> 5;
  int r0 = blockIdx.y * 32;
  int c0 = blockIdx.x * 32;
#pragma unroll
  for (int r = 0; r < 4; r++)
    t[ty + r * 8][tx] = qkv_lin[(long)(r0 + ty + r * 8) * 3072 + 2560 + c0 + tx];
  __syncthreads();
#pragma unroll
  for (int r = 0; r < 4; r++)
    out[(long)(c0 + ty + r * 8) * 1024 + r0 + tx] = f2bf(t[tx][ty + r * 8]);
}

// ---------------- flash attention: swapped QK^T + register prefetch ----------
// one block per (head, 64-q-tile); 4 waves, each 16 q rows (q = lane&15).
#define LOADK(K0, K1, tile) do {                                               \
    const unsigned short* kp_ = kb + (long)((tile) * 64 + lr) * 512 + kvh * 64 + lk * 8; \
    _Pragma("unroll") for (int f_ = 0; f_ < 4; f_++) {                         \
      K0[f_] = *reinterpret_cast<const bf16x8*>(kp_ + (long)f_ * 16 * 512);    \
      K1[f_] = *reinterpret_cast<const bf16x8*>(kp_ + (long)f_ * 16 * 512 + 32); \
    }                                                                          \
  } while (0)

#define BODY(KC0, KC1, KN0, KN1, tile) do {                                    \
    const int s0_ = (tile) * 64;                                               \
    const unsigned short* vp_ = vtb + (long)(kvh * 64 + lr) * 1024 + s0_ + lk * 8; \
    bf16x8 vfr[8];                                                             \
    _Pragma("unroll") for (int fd = 0; fd < 4; fd++) {                         \
      vfr[fd]     = *reinterpret_cast<const bf16x8*>(vp_ + (long)fd * 16 * 1024);      \
      vfr[4 + fd] = *reinterpret_cast<const bf16x8*>(vp_ + (long)fd * 16 * 1024 + 32); \
    }                                                                          \
    f32x4 sacc[4];                                                             \
    __builtin_amdgcn_s_setprio(1);                                             \
    _Pragma("unroll") for (int f = 0; f < 4; f++) {                            \
      sacc[f] = __builtin_amdgcn_mfma_f32_16x16x32_bf16(KC0[f], qa0, z4, 0, 0, 0);      \
      sacc[f] = __builtin_amdgcn_mfma_f32_16x16x32_bf16(KC1[f], qa1, sacc[f], 0, 0, 0); \
    }                                                                          \
    __builtin_amdgcn_s_setprio(0);                                             \
    if ((tile) + 1 < ntiles) LOADK(KN0, KN1, (tile) + 1);                      \
    const bool diag_ = ((tile) == qt);                                         \
    float sv[4][4];                                                            \
    float tmax_ = -3.0e38f;                                                    \
    _Pragma("unroll") for (int f = 0; f < 4; f++)                              \
      _Pragma("unroll") for (int p = 0; p < 4; p++) {                          \
        float s_ = sacc[f][p] * SC;                                            \
        if (diag_ && (f * 16 + lk * 4 + p) > qrel) s_ = -3.0e38f;              \
        sv[f][p] = s_;                                                         \
        tmax_ = fmaxf(tmax_, s_);                                              \
      }                                                                        \
    tmax_ = fmaxf(tmax_, __shfl_xor(tmax_, 16));                               \
    tmax_ = fmaxf(tmax_, __shfl_xor(tmax_, 32));                               \
    float mn_ = fmaxf(m2, tmax_);                                              \
    float r_ = exp2f(m2 - mn_);                                                \
    m2 = mn_;                                                                  \
    float rp_[4];                                                              \
    _Pragma("unroll") for (int p = 0; p < 4; p++)                              \
      rp_[p] = __shfl(r_, (lane & 48) | (lk * 4 + p));                         \
    float ps_ = 0.f;                                                           \
    _Pragma("unroll") for (int f = 0; f < 4; f++) {                            \
      float e0 = exp2f(sv[f][0] - mn_), e1 = exp2f(sv[f][1] - mn_);            \
      float e2 = exp2f(sv[f][2] - mn_), e3 = exp2f(sv[f][3] - mn_);            \
      ps_ += (e0 + e1) + (e2 + e3);                                            \
      uint2 pk_;                                                               \
      pk_.x = (unsigned)f2bf(e0) | ((unsigned)f2bf(e1) << 16);                 \
      pk_.y = (unsigned)f2bf(e2) | ((unsigned)f2bf(e3) << 16);                 \
      *reinterpret_cast<uint2*>(pbase + lr * 128 + ((f * 32 + lk * 8) ^ pswz)) = pk_; \
    }                                                                          \
    lp = lp * r_ + ps_;                                                        \
    _Pragma("unroll") for (int fd = 0; fd < 4; fd++)                           \
      _Pragma("unroll") for (int p = 0; p < 4; p++) o[fd][p] *= rp_[p];        \
    __builtin_amdgcn_s_setprio(1);                                             \
    _Pragma("unroll") for (int ks = 0; ks < 2; ks++) {                         \
      bf16x8 pa_ = *reinterpret_cast<const bf16x8*>(                           \
          pbase + lr * 128 + ((ks * 64 + lk * 16) ^ pswz));                    \
      _Pragma("unroll") for (int fd = 0; fd < 4; fd++)                         \
        o[fd] = __builtin_amdgcn_mfma_f32_16x16x32_bf16(pa_, vfr[ks * 4 + fd], o[fd], 0, 0, 0); \
    }                                                                          \
    __builtin_amdgcn_s_setprio(0);                                             \
  } while (0)

__global__ __launch_bounds__(256) void k_flash(
    const unsigned short* __restrict__ qb, const unsigned short* __restrict__ kb,
    const unsigned short* __restrict__ vtb, unsigned short* __restrict__ ao) {
  __shared__ unsigned short plds[4 * 16 * 64];
  const int h = blockIdx.y;
  const int qt = gridDim.x - 1 - blockIdx.x;  // longest-first
  const int kvh = h >> 2;
  const int lane = threadIdx.x & 63;
  const int wave = threadIdx.x >> 6;
  const int lr = lane & 15, lk = lane >> 4;
  const int qrow = qt * 64 + wave * 16;
  const int qrel = wave * 16 + lr;
  const int pswz = (lr & 7) << 4;
  char* pbase = (char*)plds + wave * 2048;
  const float SC = 0.125f * 1.44269504f;  // 1/sqrt(64) * log2(e)
  const f32x4 z4 = {0.f, 0.f, 0.f, 0.f};

  const unsigned short* qp = qb + (long)(qrow + lr) * (NH * HD) + h * HD + lk * 8;
  bf16x8 qa0 = *reinterpret_cast<const bf16x8*>(qp);
  bf16x8 qa1 = *reinterpret_cast<const bf16x8*>(qp + 32);

  f32x4 o[4];
#pragma unroll
  for (int f = 0; f < 4; f++) o[f] = z4;
  float m2 = -3.0e38f;  // running max (exp2 domain), per-lane q-row = lr
  float lp = 0.f;       // lane-partial softmax denominator

  const int ntiles = qt + 1;
  bf16x8 kA0[4], kA1[4], kB0[4], kB1[4];
  LOADK(kA0, kA1, 0);
  for (int t = 0; t < ntiles; t += 2) {
    BODY(kA0, kA1, kB0, kB1, t);
    if (t + 1 >= ntiles) break;
    BODY(kB0, kB1, kA0, kA1, t + 1);
  }

  // final: reduce lane-partial l across lk groups, broadcast to O-domain
  lp += __shfl_xor(lp, 16);
  lp += __shfl_xor(lp, 32);
  float lo[4];
#pragma unroll
  for (int p = 0; p < 4; p++) lo[p] = __shfl(lp, (lane & 48) | (lk * 4 + p));
#pragma unroll
  for (int fd = 0; fd < 4; fd++)
#pragma unroll
    for (int p = 0; p < 4; p++) {
      int qg = qrow + lk * 4 + p;
      int d = fd * 16 + lr;
      ao[(long)qg * (NH * HD) + h * HD + d] = f2bf(o[fd][p] / lo[p]);
    }
}

extern "C" void kernel_launch(void* const* d_in, const int* in_sizes, int n_in,
                              void* d_out, int out_size, void* d_ws, size_t ws_size,
                              hipStream_t stream) {
  const float* x    = (const float*)d_in[0];
  const float* cosT = (const float*)d_in[3];
  const float* sinT = (const float*)d_in[5];
  const float* Wq   = (const float*)d_in[7];
  const float* Wk   = (const float*)d_in[8];
  const float* Wv   = (const float*)d_in[9];
  const float* Wo   = (const float*)d_in[10];
  const float* qw   = (const float*)d_in[11];
  const float* kw   = (const float*)d_in[12];
  float* out = (float*)d_out;

  char* ws = (char*)d_ws;
  unsigned short* xb    = (unsigned short*)(ws);               // 4 MB
  unsigned short* Wqkv  = (unsigned short*)(ws + (4u << 20));  // 12 MB [3072][2048]
  unsigned short* Wob   = (unsigned short*)(ws + (16u << 20)); // 8 MB
  float* qkv_lin = (float*)(ws + (24u << 20));                 // 12 MB [1024][3072]
  unsigned short* qbb = (unsigned short*)(ws + (36u << 20));   // 4 MB
  unsigned short* kbb = (unsigned short*)(ws + (40u << 20));   // 1 MB
  unsigned short* vtb = (unsigned short*)(ws + (41u << 20));   // 1 MB
  unsigned short* ao  = (unsigned short*)(ws + (42u << 20));   // 4 MB

  // all fp32 -> bf16 conversions in one launch (12M elems, 4/thread)
  k_cvt_all<<<12288, 256, 0, stream>>>(x, Wq, Wk, Wv, Wo, xb, Wqkv, Wob);

  // fused QKV projection: [1024][3072] = x * Wqkv^T
  k_gemm2<<<dim3(24, 16), 256, 0, stream>>>(xb, Wqkv, qkv_lin, 3072, 2048);

  // RMSNorm + RoPE -> bf16 q/k
  k_norm_rope<<<(T_TOK * (NH + NKV) * 64) / 256, 256, 0, stream>>>(
      qkv_lin, qbb, kbb, cosT, sinT, qw, kw);

  // V^T bf16 for PV B-operand
  k_vt<<<dim3(16, 32), 256, 0, stream>>>(qkv_lin, vtb);

  // flash attention -> bf16 [T][H*HD]
  k_flash<<<dim3(16, 32), 256, 0, stream>>>(qbb, kbb, vtb, ao);

  // output projection -> fp32 d_out
  k_gemm2<<<dim3(16, 16), 256, 0, stream>>>(ao, Wob, out, 2048, 2048);
}